// Round 9
// baseline (208.130 us; speedup 1.0000x reference)
//
#include <hip/hip_runtime.h>
#include <math.h>

#define N_EMB 1024
#define D_EMB 512
#define LN_N  6.9314718056f   // ln(1024)

typedef float f32x4 __attribute__((ext_vector_type(4)));  // native vec4 for NT stores

// One WAVE per row, TWO rows per wave (depth-2 ILP pipeline).
// All 16 KB of loads for both rows are issued before any compute, so row 1's
// HBM latency hides under row 0's transcendentals. No LDS, no __syncthreads.
__global__ __launch_bounds__(256) void gumbel_quantize_kernel(
    const float* __restrict__ logits,   // [rows, 1024]
    const float* __restrict__ u,        // [rows, 1024]
    const float* __restrict__ embed,    // [1024, 512]
    float*       __restrict__ zq,       // [rows, 512]
    float*       __restrict__ diff,     // [rows, 1024]
    float*       __restrict__ indf,     // [rows]
    int waves_total)                    // rows/2
{
    const int lane = threadIdx.x & 63;
    const int wave = threadIdx.x >> 6;
    const int wid  = blockIdx.x * 4 + wave;

    const int r0 = wid;
    const int r1 = wid + waves_total;

    // ---- issue ALL loads up front (16 dwordx4 per lane, 16 KB/wave) ----
    f32x4 l4[2][4], u4[2][4];
    {
        const f32x4* lp0 = (const f32x4*)(logits + (size_t)r0 * N_EMB);
        const f32x4* up0 = (const f32x4*)(u      + (size_t)r0 * N_EMB);
        const f32x4* lp1 = (const f32x4*)(logits + (size_t)r1 * N_EMB);
        const f32x4* up1 = (const f32x4*)(u      + (size_t)r1 * N_EMB);
        #pragma unroll
        for (int c = 0; c < 4; ++c) l4[0][c] = lp0[c * 64 + lane];
        #pragma unroll
        for (int c = 0; c < 4; ++c) u4[0][c] = up0[c * 64 + lane];
        #pragma unroll
        for (int c = 0; c < 4; ++c) l4[1][c] = lp1[c * 64 + lane];
        #pragma unroll
        for (int c = 0; c < 4; ++c) u4[1][c] = up1[c * 64 + lane];
    }

    #pragma unroll
    for (int p = 0; p < 2; ++p) {
        const int row = (p == 0) ? r0 : r1;
        const size_t rbase = (size_t)row * N_EMB;

        float lv[16], uv[16];
        #pragma unroll
        for (int c = 0; c < 4; ++c) {
            #pragma unroll
            for (int j = 0; j < 4; ++j) {
                lv[c*4+j] = l4[p][c][j];
                uv[c*4+j] = u4[p][c][j];
            }
        }

        // ---- gumbel-perturbed argmax (libm logf: argmax-critical) + max ----
        float smax = -INFINITY; int sidx = 0;
        float lmax = -INFINITY;
        #pragma unroll
        for (int c = 0; c < 4; ++c) {
            #pragma unroll
            for (int j = 0; j < 4; ++j) {
                const int k = c * 4 + j;
                const float g  = -logf(-logf(uv[k]));   // gumbel noise
                const float sc = lv[k] + g;             // tau == 1.0
                const int idx  = c * 256 + lane * 4 + j;
                if (sc > smax) { smax = sc; sidx = idx; }  // first-idx ties
                lmax = fmaxf(lmax, lv[k]);
            }
        }

        // ---- wave butterfly: argmax(score) + max(logit) ----
        #pragma unroll
        for (int off = 32; off > 0; off >>= 1) {
            const float v2 = __shfl_xor(smax, off, 64);
            const int   i2 = __shfl_xor(sidx, off, 64);
            if (v2 > smax || (v2 == smax && i2 < sidx)) { smax = v2; sidx = i2; }
            lmax = fmaxf(lmax, __shfl_xor(lmax, off, 64));
        }
        const int   ind = sidx;
        const float m   = lmax;

        // ---- softmax denominator (hw exp; diff threshold is huge) ----
        float psum = 0.f;
        #pragma unroll
        for (int j = 0; j < 16; ++j) psum += __expf(lv[j] - m);
        #pragma unroll
        for (int off = 32; off > 0; off >>= 1) psum += __shfl_xor(psum, off, 64);
        const float sum = psum;                  // same on all lanes
        const float L   = LN_N - logf(sum);      // ln(N/sum), once per row

        // ---- diff = -ln(qy*N)/qy = -((lv-m)+L) * sum * exp(m-lv) ----
        f32x4* dp = (f32x4*)(diff + rbase);
        #pragma unroll
        for (int c = 0; c < 4; ++c) {
            f32x4 d;
            #pragma unroll
            for (int j = 0; j < 4; ++j) {
                const int k = c * 4 + j;
                d[j] = -((lv[k] - m) + L) * sum * __expf(m - lv[k]);
            }
            __builtin_nontemporal_store(d, dp + c * 64 + lane);
        }

        // ---- z_q row = embed[ind] (2 KB gather, L2-hot) ----
        const f32x4* erow = (const f32x4*)(embed + (size_t)ind * D_EMB);
        f32x4*       zrow = (f32x4*)(zq + (size_t)row * D_EMB);
        #pragma unroll
        for (int c = 0; c < 2; ++c)
            __builtin_nontemporal_store(erow[c * 64 + lane], zrow + c * 64 + lane);

        if (lane == 0) __builtin_nontemporal_store((float)ind, indf + row);
    }
}

extern "C" void kernel_launch(void* const* d_in, const int* in_sizes, int n_in,
                              void* d_out, int out_size, void* d_ws, size_t ws_size,
                              hipStream_t stream) {
    const float* logits = (const float*)d_in[0];
    const float* u      = (const float*)d_in[1];
    const float* embed  = (const float*)d_in[2];

    const int rows = in_sizes[0] / N_EMB;   // 8*2048 = 16384

    float* out  = (float*)d_out;
    float* zq   = out;                                   // rows*512
    float* diff = zq + (size_t)rows * D_EMB;             // rows*1024
    float* indf = diff + (size_t)rows * N_EMB;           // rows

    const int waves_total = rows / 2;       // 8192 waves, 2 rows each
    const int blocks      = waves_total / 4; // 2048 blocks (8/CU)

    gumbel_quantize_kernel<<<blocks, 256, 0, stream>>>(logits, u, embed,
                                                       zq, diff, indf,
                                                       waves_total);
}